// Round 13
// baseline (76.705 us; speedup 1.0000x reference)
//
#include <hip/hip_runtime.h>

// LBP for semantic dependency parsing — label-difference form, all 3
// iterations fused, u-SPACE chain (u = 2^D), fp16 F payload, double-buffered
// global_load_lds staging with COUNTED vmcnt. This round: 512-thr blocks,
// LDS ~55 KB -> 2 blocks/CU, so one block's pure-compute passes 2-3 overlap
// the other block's HBM staging (r12 post-mortem: 107 KB LDS = 1 block/CU
// serialized mem-phase and compute-phase per CU; VALUBusy pinned at 34%).
//
//   F[b,i,j,k] = 2^(log2e*s) = e^s                (only use of the scores)
//   u_1 = (p1 + F)*r1,          p1 = 2^(-q0[i]), r1 = 1/(1+p1)
//   u_t = (p + F)/(1 + p),      p = u_{t-1} * 2^(-q_{t-1}[i])
//   q_t[k] = q0[k] + mask[k] * sum_i log2(u_s*u_c*u_g)[i,k]
//                               * mask[i]*(i!=j)*(i!=k)
//   out[b,k,j] = 1/(1+2^(-q_3[k]))
//
// Geometry: block (b,j), 512 thr, 8 waves; thread = (kq=t&31 -> 4 k's,
// rg=t>>5 -> rows rg+16r, r=0..7). Wave wv owns rows {2wv,2wv+1}(+16r):
// DMAs them into its private double-buffered LDS slot (3 tensors x 1 KB),
// counted vmcnt(3) keeps the next tile in flight. Pass 3 recomputes the
// chain from F (2 rcp/score) instead of storing u2 — keeps VGPR <= 128 so
// 2 blocks/CU actually fit. fp16 F precision proven r7-r12 (absmax 0.0078).

#define TS 128

typedef float    f4v __attribute__((ext_vector_type(4)));
typedef _Float16 h4v __attribute__((ext_vector_type(4)));

constexpr float LOG2E = 1.4426950408889634f;

__device__ __forceinline__ float rcpf(float x)   { return __builtin_amdgcn_rcpf(x); }
__device__ __forceinline__ float clampe(float e) { return fminf(fmaxf(e, -126.0f), 60.0f); }

__device__ __forceinline__ void gload_lds16(const float* g, float* l) {
    __builtin_amdgcn_global_load_lds((const __attribute__((address_space(1))) void*)g,
                                     (__attribute__((address_space(3))) void*)l,
                                     16, 0, 0);
}

// ---- single-block mask format probe: f[0]!=0 byte mask, f[1]!=0 f32, else i32
__global__ void mask_probe(const unsigned char* __restrict__ m, int n, int* __restrict__ f) {
    __shared__ int s1, s23;
    if (threadIdx.x == 0) { s1 = 0; s23 = 0; }
    __syncthreads();
    unsigned a1 = 0, a23 = 0;
    const int n16 = n >> 4;
    const uint4* m4 = (const uint4*)m;
    for (int i = threadIdx.x; i < n16; i += 1024) {
        const uint4 v = m4[i];
        const unsigned o = v.x | v.y | v.z | v.w;
        a1  |= o & 0x0000FF00u;
        a23 |= o & 0xFFFF0000u;
    }
    for (int i = (n16 << 4) + threadIdx.x; i < n; i += 1024) {  // tail bytes
        const unsigned char b = m[i];
        const int r = i & 3;
        if (r == 1) a1 |= b;
        if (r >= 2) a23 |= b;
    }
    if (__any(a1 != 0)  && (threadIdx.x & 63) == 0) atomicOr(&s1, 1);
    if (__any(a23 != 0) && (threadIdx.x & 63) == 0) atomicOr(&s23, 1);
    __syncthreads();
    if (threadIdx.x == 0) { f[0] = s1; f[1] = s23; }
}

__global__ __launch_bounds__(512, 4)
void lbp_fused(const float* __restrict__ s_edge,
               const float* __restrict__ sib,
               const float* __restrict__ cop,
               const float* __restrict__ grd,
               const void* __restrict__ mask,
               const int* __restrict__ flags,
               float* __restrict__ outp)
{
    __shared__ float ldsS[8][2][2][TS];    // 16 KB: [wave][slot][rowpair][k]
    __shared__ float ldsC[8][2][2][TS];
    __shared__ float ldsG[8][2][2][TS];
    __shared__ f4v red4[8 * 32];           // 4 KB: [wave][k-quad]
    __shared__ float q0s[TS], p1s[TS], r1s[TS], g1s[TS], g2s[TS];
    __shared__ unsigned char mrow[TS];

    const int bj = blockIdx.x;
    const int b  = bj >> 7;
    const int j  = bj & (TS - 1);
    const int t  = threadIdx.x;
    const int kq = t & 31;              // k = 4*kq .. 4*kq+3
    const int rg = t >> 5;              // 0..15: rows rg + 16r, r=0..7
    const int k0 = kq * 4;
    const int lane = t & 63;
    const int wv = t >> 6;              // wave 0..7; owns rows {2wv,2wv+1}(+16r)
    const int sl = rg & 1;              // row slot within the wave's tile

    // ---- per-column prologue ----
    if (t < TS) {
        const int i = t;
        const int idx = (b * TS + i) * TS + j;
        const float q0 = LOG2E * s_edge[idx];
        q0s[i] = q0;
        const int f1 = flags[0], f23 = flags[1];
        unsigned char mv;
        if (f1)       mv = ((const unsigned char*)mask)[idx] != 0;
        else if (f23) mv = ((const float*)mask)[idx] != 0.0f;
        else          mv = ((const int*)mask)[idx]   != 0;
        mrow[i] = mv;
        const float p1 = exp2f(clampe(-q0));
        p1s[i] = p1;
        r1s[i] = rcpf(1.0f + p1);
    }
    __syncthreads();

    // per-lane global element offset: row 2wv+(lane>>5) (+16r), k = 4*(lane&31);
    // LDS dest is linear (lane*16B), matching the [2][TS] tile layout
    const size_t gcol = ((size_t)(b * TS) * TS + j) * TS;
    const size_t gLane = gcol + (size_t)(2 * wv + (lane >> 5)) * (TS * TS) + 4 * (lane & 31);

    // ---- prologue DMA: tile 0 into slot 0 ----
    gload_lds16(sib + gLane, &ldsS[wv][0][0][0]);
    gload_lds16(cop + gLane, &ldsC[wv][0][0][0]);
    gload_lds16(grd + gLane, &ldsG[wv][0][0][0]);

    // ---- stage (double-buffered DMA, barrier-free) + pass 1 ----
    h4v Fs[8], Fc[8], Fg[8];
    f4v acc = {0.0f, 0.0f, 0.0f, 0.0f};
    #pragma unroll
    for (int r = 0; r < 8; ++r) {
        if (r < 7) {
            // prior ds_reads of the slot we are about to overwrite are done
            asm volatile("s_waitcnt lgkmcnt(0)" ::: "memory");
            const size_t g = gLane + (size_t)(16 * (r + 1)) * (TS * TS);
            const int s = (r + 1) & 1;
            gload_lds16(sib + g, &ldsS[wv][s][0][0]);
            gload_lds16(cop + g, &ldsC[wv][s][0][0]);
            gload_lds16(grd + g, &ldsG[wv][s][0][0]);
            asm volatile("s_waitcnt vmcnt(3)" ::: "memory");   // tile r landed; r+1 in flight
        } else {
            asm volatile("s_waitcnt vmcnt(0)" ::: "memory");
        }
        const int s0 = r & 1;
        const f4v vs = *(const f4v*)&ldsS[wv][s0][sl][k0];
        const f4v vc = *(const f4v*)&ldsC[wv][s0][sl][k0];
        const f4v vg = *(const f4v*)&ldsG[wv][s0][sl][k0];

        const int i = rg + 16 * r;
        f4v fs, fc, fg;
        #pragma unroll
        for (int c = 0; c < 4; ++c) {
            fs[c] = exp2f(LOG2E * vs[c]);
            fc[c] = exp2f(LOG2E * vc[c]);
            fg[c] = exp2f(LOG2E * vg[c]);
        }
        Fs[r] = __builtin_convertvector(fs, h4v);
        Fc[r] = __builtin_convertvector(fc, h4v);
        Fg[r] = __builtin_convertvector(fg, h4v);
        const bool live = (mrow[i] != 0) && (i != j);
        const float p1 = p1s[i], r1 = r1s[i];
        #pragma unroll
        for (int c = 0; c < 4; ++c) {
            const float us = (p1 + fs[c]) * r1;
            const float uc = (p1 + fc[c]) * r1;
            const float ug = (p1 + fg[c]) * r1;
            const float l  = __log2f(us * uc * ug);
            if (live && (i != k0 + c)) acc[c] += l;
        }
    }

    // reduce -> q1 -> g1
    #pragma unroll
    for (int c = 0; c < 4; ++c) acc[c] += __shfl_xor(acc[c], 32);
    if (lane < 32) red4[wv * 32 + lane] = acc;
    __syncthreads();
    if (t < TS) {
        const float* red = (const float*)red4;
        float tot = 0.0f;
        #pragma unroll
        for (int w = 0; w < 8; ++w) tot += red[w * TS + t];
        const float q1 = q0s[t] + (mrow[t] ? tot : 0.0f);
        g1s[t] = exp2f(clampe(-q1));
    }
    __syncthreads();

    // ---- pass 2: u2 via 1 rcp/score, pure register math ----
    acc[0] = acc[1] = acc[2] = acc[3] = 0.0f;
    #pragma unroll
    for (int r = 0; r < 8; ++r) {
        const int i = rg + 16 * r;
        const bool live = (mrow[i] != 0) && (i != j);
        if (live) {
            const float p1 = p1s[i], r1 = r1s[i], g1 = g1s[i];
            const f4v fs = __builtin_convertvector(Fs[r], f4v);
            const f4v fc = __builtin_convertvector(Fc[r], f4v);
            const f4v fg = __builtin_convertvector(Fg[r], f4v);
            #pragma unroll
            for (int c = 0; c < 4; ++c) {
                float p, us, uc, ug;
                us = (p1 + fs[c]) * r1;  p = us * g1;  us = (p + fs[c]) * rcpf(1.0f + p);
                uc = (p1 + fc[c]) * r1;  p = uc * g1;  uc = (p + fc[c]) * rcpf(1.0f + p);
                ug = (p1 + fg[c]) * r1;  p = ug * g1;  ug = (p + fg[c]) * rcpf(1.0f + p);
                const float l = __log2f(us * uc * ug);
                if (i != k0 + c) acc[c] += l;
            }
        }
    }

    // reduce -> q2 -> g2
    #pragma unroll
    for (int c = 0; c < 4; ++c) acc[c] += __shfl_xor(acc[c], 32);
    if (lane < 32) red4[wv * 32 + lane] = acc;
    __syncthreads();
    if (t < TS) {
        const float* red = (const float*)red4;
        float tot = 0.0f;
        #pragma unroll
        for (int w = 0; w < 8; ++w) tot += red[w * TS + t];
        const float q2 = q0s[t] + (mrow[t] ? tot : 0.0f);
        g2s[t] = exp2f(clampe(-q2));
    }
    __syncthreads();

    // ---- pass 3: full chain recompute from F (2 rcp/score) ----
    acc[0] = acc[1] = acc[2] = acc[3] = 0.0f;
    #pragma unroll
    for (int r = 0; r < 8; ++r) {
        const int i = rg + 16 * r;
        const bool live = (mrow[i] != 0) && (i != j);
        if (live) {
            const float p1 = p1s[i], r1 = r1s[i], g1 = g1s[i], g2 = g2s[i];
            const f4v fs = __builtin_convertvector(Fs[r], f4v);
            const f4v fc = __builtin_convertvector(Fc[r], f4v);
            const f4v fg = __builtin_convertvector(Fg[r], f4v);
            #pragma unroll
            for (int c = 0; c < 4; ++c) {
                float p, us, uc, ug;
                us = (p1 + fs[c]) * r1;  p = us * g1;  us = (p + fs[c]) * rcpf(1.0f + p);
                p = us * g2;  us = (p + fs[c]) * rcpf(1.0f + p);
                uc = (p1 + fc[c]) * r1;  p = uc * g1;  uc = (p + fc[c]) * rcpf(1.0f + p);
                p = uc * g2;  uc = (p + fc[c]) * rcpf(1.0f + p);
                ug = (p1 + fg[c]) * r1;  p = ug * g1;  ug = (p + fg[c]) * rcpf(1.0f + p);
                p = ug * g2;  ug = (p + fg[c]) * rcpf(1.0f + p);
                const float l = __log2f(us * uc * ug);
                if (i != k0 + c) acc[c] += l;
            }
        }
    }

    // reduce -> q3 -> output
    #pragma unroll
    for (int c = 0; c < 4; ++c) acc[c] += __shfl_xor(acc[c], 32);
    if (lane < 32) red4[wv * 32 + lane] = acc;
    __syncthreads();
    if (t < TS) {
        const float* red = (const float*)red4;
        float tot = 0.0f;
        #pragma unroll
        for (int w = 0; w < 8; ++w) tot += red[w * TS + t];
        const float q3 = q0s[t] + (mrow[t] ? tot : 0.0f);
        outp[(b * TS + t) * TS + j] = 1.0f / (1.0f + exp2f(clampe(-q3)));
    }
}

extern "C" void kernel_launch(void* const* d_in, const int* in_sizes, int n_in,
                              void* d_out, int out_size, void* d_ws, size_t ws_size,
                              hipStream_t stream) {
    const float* s_edge = (const float*)d_in[0];
    const float* sib    = (const float*)d_in[1];
    const float* cop    = (const float*)d_in[2];
    const float* grd    = (const float*)d_in[3];
    const void*  mask   = d_in[4];
    float* out = (float*)d_out;

    const int Bn = in_sizes[0] / (TS * TS);   // batch
    const int nMask = in_sizes[4];            // B*S*S elements

    int* flags = (int*)d_ws;

    mask_probe<<<1, 1024, 0, stream>>>((const unsigned char*)mask, nMask, flags);
    lbp_fused<<<Bn * TS, 512, 0, stream>>>(s_edge, sib, cop, grd, mask, flags, out);
}